// Round 1
// baseline (71.920 us; speedup 1.0000x reference)
//
#include <hip/hip_runtime.h>

#define NN 8192
#define DD 256   // 512 bytes per bf16 row

typedef __bf16 bf16x8 __attribute__((ext_vector_type(8)));
typedef float  f32x4  __attribute__((ext_vector_type(4)));

// round-to-nearest-even f32 -> bf16 bits
__device__ __forceinline__ unsigned short f2bf(float f) {
    unsigned u = __float_as_uint(f);
    return (unsigned short)((u + 0x7fffu + ((u >> 16) & 1u)) >> 16);
}

// async global -> LDS, 16B per lane (global_load_lds_dwordx4)
__device__ __forceinline__ void gload16(const void* g, void* l) {
    __builtin_amdgcn_global_load_lds((const __attribute__((address_space(1))) void*)g,
                                     (__attribute__((address_space(3))) void*)l,
                                     16, 0, 0);
}

// ---------------- kernel 1: normalize rows -> bf16, zero rowsum ----------------
__global__ __launch_bounds__(256) void ntxent_norm(const float* __restrict__ z,
                                                   char* __restrict__ znB,
                                                   float* __restrict__ rowsum)
{
    const int t = threadIdx.x;
    const int l = t & 63;
    const int w = t >> 6;
    const int row = blockIdx.x * 4 + w;   // one wave per row

    float4 v = ((const float4*)(z + (size_t)row * DD))[l];
    float ss = v.x * v.x + v.y * v.y + v.z * v.z + v.w * v.w;
    ss += __shfl_xor(ss, 1);  ss += __shfl_xor(ss, 2);  ss += __shfl_xor(ss, 4);
    ss += __shfl_xor(ss, 8);  ss += __shfl_xor(ss, 16); ss += __shfl_xor(ss, 32);
    const float inv = 1.0f / fmaxf(sqrtf(ss), 1e-8f);

    uint2 o;
    o.x = (unsigned)f2bf(v.x * inv) | ((unsigned)f2bf(v.y * inv) << 16);
    o.y = (unsigned)f2bf(v.z * inv) | ((unsigned)f2bf(v.w * inv) << 16);
    ((uint2*)(znB + (size_t)row * 512))[l] = o;

    if (blockIdx.x < 32) rowsum[blockIdx.x * 256 + t] = 0.0f;  // 32*256 = 8192
}

// ---------------- kernel 2: fused sim GEMM + exp accumulate ----------------
// grid: 64 row-tiles (128 rows) x 16 j-splits (512 cols each) = 1024 blocks
__global__ __launch_bounds__(256, 2) void ntxent_sim(const char* __restrict__ znB,
                                                     float* __restrict__ rowsum,
                                                     float* __restrict__ possum)
{
    __shared__ char sA[16384];   // 128 rows x 128B (BK=64 bf16), XOR-swizzled
    __shared__ char sB[16384];
    __shared__ float psh[4];

    const int t  = threadIdx.x;
    const int l  = t & 63;
    const int w  = t >> 6;      // wave 0..3
    const int wr = w >> 1;      // row half
    const int wc = w & 1;       // col half
    const int lm = l & 15;
    const int lh = l >> 4;      // 0..3

    const int rt = blockIdx.x >> 4;
    const int js = blockIdx.x & 15;
    const int rowbase = rt * 128;
    const int arow0 = wr * 64;
    const int bcol0 = wc * 64;

    const f32x4 vzero = {0.0f, 0.0f, 0.0f, 0.0f};

    float rsum[16];
#pragma unroll
    for (int q = 0; q < 16; ++q) rsum[q] = 0.0f;
    float psum = 0.0f;

#pragma unroll 1
    for (int jt = 0; jt < 4; ++jt) {
        const int jcb = js * 512 + jt * 128;   // global col base of this j-tile
        f32x4 acc[4][4];
#pragma unroll
        for (int r = 0; r < 4; ++r)
#pragma unroll
            for (int c = 0; c < 4; ++c) acc[r][c] = vzero;

#pragma unroll 1
        for (int bk = 0; bk < 4; ++bk) {
            __syncthreads();   // all waves done reading sA/sB from previous step
            // stage A rows (rowbase..+127) and B rows (jcb..+127), k-bytes [bk*128, +128)
            // LDS linear dest; source address carries the (row&7)<<4 XOR swizzle.
#pragma unroll
            for (int p = 0; p < 4; ++p) {
                const int flat = p * 4096 + t * 16;
                const int row = flat >> 7;
                const int kb  = flat & 127;
                const int skb = (kb ^ ((row & 7) << 4));
                gload16(znB + (size_t)(rowbase + row) * 512 + bk * 128 + skb, sA + flat);
                gload16(znB + (size_t)(jcb + row) * 512 + bk * 128 + skb, sB + flat);
            }
            asm volatile("s_waitcnt vmcnt(0)" ::: "memory");
            __syncthreads();
#pragma unroll
            for (int kw = 0; kw < 2; ++kw) {
                const int kt = kw * 64 + lh * 16;   // byte offset within BK chunk
                bf16x8 af[4], bfr[4];
#pragma unroll
                for (int s = 0; s < 4; ++s) {
                    const int ar = arow0 + s * 16 + lm;
                    af[s]  = *(const bf16x8*)(sA + ar * 128 + (kt ^ ((ar & 7) << 4)));
                    const int bc = bcol0 + s * 16 + lm;
                    bfr[s] = *(const bf16x8*)(sB + bc * 128 + (kt ^ ((bc & 7) << 4)));
                }
#pragma unroll
                for (int r = 0; r < 4; ++r)
#pragma unroll
                    for (int c = 0; c < 4; ++c)
                        acc[r][c] = __builtin_amdgcn_mfma_f32_16x16x32_bf16(af[r], bfr[c], acc[r][c], 0, 0, 0);
            }
        }

        // epilogue for this j-tile (registers only; next bk=0 barrier protects LDS)
#pragma unroll
        for (int r = 0; r < 4; ++r) {
            const int ib = rowbase + arow0 + r * 16 + lh * 4;
#pragma unroll
            for (int c = 0; c < 4; ++c) {
                const int j = jcb + bcol0 + c * 16 + lm;
#pragma unroll
                for (int q = 0; q < 4; ++q) {
                    const int i = ib + q;
                    const float lg = 2.0f * acc[r][c][q];   // logits = sim / 0.5
                    const float e = __expf(lg);
                    rsum[r * 4 + q] += (j == i) ? 0.0f : e;       // exact diag exclusion
                    psum += (j == (i ^ 1)) ? lg : 0.0f;           // positive pair
                }
            }
        }
    }

    // reduce rsum over the 16 lanes (cols) of each lh group, then atomicAdd per row
#pragma unroll
    for (int q = 0; q < 16; ++q) {
        float v = rsum[q];
        v += __shfl_xor(v, 1); v += __shfl_xor(v, 2);
        v += __shfl_xor(v, 4); v += __shfl_xor(v, 8);
        rsum[q] = v;
    }
    if (lm == 0) {
#pragma unroll
        for (int r = 0; r < 4; ++r)
#pragma unroll
            for (int q = 0; q < 4; ++q) {
                const int i = rowbase + arow0 + r * 16 + lh * 4 + q;
                atomicAdd(&rowsum[i], rsum[r * 4 + q]);
            }
    }

    // positive-pair logits: full reduce, one value per block (deterministic)
    float p = psum;
    p += __shfl_xor(p, 1);  p += __shfl_xor(p, 2);  p += __shfl_xor(p, 4);
    p += __shfl_xor(p, 8);  p += __shfl_xor(p, 16); p += __shfl_xor(p, 32);
    if (l == 0) psh[w] = p;
    __syncthreads();
    if (t == 0) possum[blockIdx.x] = psh[0] + psh[1] + psh[2] + psh[3];
}

// ---------------- kernel 3: final scalar ----------------
__global__ __launch_bounds__(256) void ntxent_final(const float* __restrict__ rowsum,
                                                    const float* __restrict__ possum,
                                                    float* __restrict__ out)
{
    __shared__ float sh[4];
    const int t = threadIdx.x;
    float s = 0.0f;
#pragma unroll 1
    for (int i = t; i < NN; i += 256) s += logf(rowsum[i]);
    s -= possum[t] + possum[t + 256] + possum[t + 512] + possum[t + 768];
    s += __shfl_xor(s, 1);  s += __shfl_xor(s, 2);  s += __shfl_xor(s, 4);
    s += __shfl_xor(s, 8);  s += __shfl_xor(s, 16); s += __shfl_xor(s, 32);
    if ((t & 63) == 0) sh[t >> 6] = s;
    __syncthreads();
    if (t == 0) out[0] = (sh[0] + sh[1] + sh[2] + sh[3]) * (1.0f / NN);
}

extern "C" void kernel_launch(void* const* d_in, const int* in_sizes, int n_in,
                              void* d_out, int out_size, void* d_ws, size_t ws_size,
                              hipStream_t stream)
{
    const float* z = (const float*)d_in[0];
    char*  znB    = (char*)d_ws;                                    // 4 MB bf16 zn
    float* rowsum = (float*)((char*)d_ws + (size_t)NN * 512);       // 32 KB
    float* possum = (float*)((char*)d_ws + (size_t)NN * 512 + (size_t)NN * 4); // 4 KB
    float* out = (float*)d_out;

    ntxent_norm <<<dim3(NN / 4), dim3(256), 0, stream>>>(z, znB, rowsum);
    ntxent_sim  <<<dim3(1024),   dim3(256), 0, stream>>>(znB, rowsum, possum);
    ntxent_final<<<dim3(1),      dim3(256), 0, stream>>>(rowsum, possum, out);
}